// Round 9
// baseline (125.073 us; speedup 1.0000x reference)
//
#include <hip/hip_runtime.h>
#include <hip/hip_fp16.h>
#include <math.h>

#define BB 8
#define CC 64
#define NN 8192
#define KK 20
#define COUT 64
#define BN_EPS 1e-5

// XCD swizzle: blockIdx round-robins over 8 XCDs, so (blockIdx.x & 7) == XCD.
// Batch b pinned to XCD b keeps b's yc slice resident in that XCD's L2.

// ---------------------------------------------------------------------------
// Pass 0: transpose/combine weights -> wt[c][128]:
//   wt[c][o]      = w[o][c] - w[o][64+c]   (o < 64)   ("wa" row)
//   wt[c][64+o']  = w[o'][64+c]            (o' < 64)  ("wb" row)
// Lets pass1 iterate c-outer / o-inner: 32 consecutive dwords per (wave,c)
// -> 2 s_load_dwordx16 feeding 32 FMAs, independent across c (prefetchable).
// ---------------------------------------------------------------------------
__global__ __launch_bounds__(256) void pass0_wt(const float* __restrict__ w,
                                                float* __restrict__ wt) {
    const int t = threadIdx.x;
    for (int idx = t; idx < 64 * 128; idx += 256) {
        const int c  = idx >> 7;
        const int o2 = idx & 127;
        float v;
        if (o2 < 64) v = w[o2 * 128 + c] - w[o2 * 128 + 64 + c];
        else         v = w[(o2 - 64) * 128 + 64 + c];
        wt[idx] = v;
    }
}

// ---------------------------------------------------------------------------
// Pass 1: yc[b][n][0..127] = wt[c][.] . x[b][c][n] over c.
// lane = n (64-wide n tile), wave wv owns o-range [wv*32, wv*32+32).
// x column in 64 VGPRs (coalesced); weights wave-uniform -> s_load.
// Block tile T[64][133] (33 KB -> 4 blocks/CU, round-8 had 66.5 KB -> 2).
// 133 pad: store bank = (133*lane + col)%32 = (5*lane+col)%32, gcd(5,32)=1
// -> 2-way (free). Store: 256 threads write full 512 B yc rows.
// ---------------------------------------------------------------------------
__global__ __launch_bounds__(256) void pass1_yc(const float* __restrict__ x,
                                                const float* __restrict__ wt,
                                                float* __restrict__ yc) {
    const int blk = blockIdx.x;          // 1024 blocks
    const int b   = blk & 7;             // XCD-aligned batch
    const int ng  = blk >> 3;            // 0..127
    const int n0  = ng * 64;
    const int tid = threadIdx.x;
    const int wv   = __builtin_amdgcn_readfirstlane(tid >> 6); // uniform
    const int lane = tid & 63;
    const int o0   = wv * 32;            // uniform o-range base

    __shared__ float T[64][133];

    // coalesced x column load: lanes consecutive in n
    const float* xb = x + (size_t)b * CC * NN + n0 + lane;
    float xr[64];
#pragma unroll
    for (int c = 0; c < 64; ++c)
        xr[c] = xb[(size_t)c * NN];

    float acc[32];
#pragma unroll
    for (int j = 0; j < 32; ++j) acc[j] = 0.f;

    const float* wp = wt + o0;           // uniform -> s_load
    for (int c = 0; c < 64; ++c) {
        const float xc = xr[c];
        const float* wr = wp + c * 128;
#pragma unroll
        for (int j = 0; j < 32; ++j)
            acc[j] = fmaf(wr[j], xc, acc[j]);
    }

#pragma unroll
    for (int j = 0; j < 32; ++j)
        T[lane][o0 + j] = acc[j];
    __syncthreads();

    // coalesced store: 8 rows per iter, 32 lanes x float4 = full 512 B row
    float* ybase = yc + ((size_t)b * NN + n0) * 128;
    const int f  = tid & 31;
    const int r0 = tid >> 5;
    for (int rr = 0; rr < 8; ++rr) {
        const int r = rr * 8 + r0;
        float4 v = {T[r][4 * f], T[r][4 * f + 1], T[r][4 * f + 2], T[r][4 * f + 3]};
        *reinterpret_cast<float4*>(ybase + (size_t)r * 128 + 4 * f) = v;
    }
}

// ---------------------------------------------------------------------------
// Pass 2 (float4-gather version).
// Lane layout: g = lane>>4 (k-slot), q = lane&15 (channel quad).
// hmm stored as fp16: row = [64 x max][64 x min] halves (256 B).
// ---------------------------------------------------------------------------
__global__ __launch_bounds__(256, 6) void pass2_gather(const float* __restrict__ yc,
                                                       const int* __restrict__ eidx,
                                                       __half* __restrict__ hmm,
                                                       float* __restrict__ psum,
                                                       float* __restrict__ pssq) {
    const int b  = blockIdx.x & 7;
    const int n0 = (blockIdx.x >> 3) * 32;
    const int w    = threadIdx.x >> 6;
    const int lane = threadIdx.x & 63;
    const int g = lane >> 4;   // k-slot 0..3
    const int q = lane & 15;   // channel quad

    const int* e0 = eidx + (size_t)b * NN * KK;   // edge_index[0]
    const int* e1 = e0 + (size_t)BB * NN * KK;    // edge_index[1]
    const float* yca = yc + (size_t)b * NN * 128 + 4 * q;        // wa half
    const float* ycb = yc + (size_t)b * NN * 128 + 64 + 4 * q;   // wb half

    float4 sum4 = {0.f, 0.f, 0.f, 0.f};
    float4 ssq4 = {0.f, 0.f, 0.f, 0.f};

    for (int i = 0; i < 8; ++i) {
        const int n = n0 + w * 8 + i;
        const int* r1 = e1 + (size_t)n * KK;
        const int* r0 = e0 + (size_t)n * KK;
        int i1k[5], i0k[5];
#pragma unroll
        for (int s = 0; s < 5; ++s) {
            i1k[s] = r1[4 * s + g];
            i0k[s] = r0[4 * s + g];
        }
        float4 mx = {-3.402823466e38f, -3.402823466e38f, -3.402823466e38f, -3.402823466e38f};
        float4 mn = { 3.402823466e38f,  3.402823466e38f,  3.402823466e38f,  3.402823466e38f};
#pragma unroll
        for (int s = 0; s < 5; ++s) {
            float4 v1 = *reinterpret_cast<const float4*>(yca + (size_t)i1k[s] * 128);
            float4 v0 = *reinterpret_cast<const float4*>(ycb + (size_t)i0k[s] * 128);
            float4 h;
            h.x = v1.x + v0.x; h.y = v1.y + v0.y;
            h.z = v1.z + v0.z; h.w = v1.w + v0.w;
            mx.x = fmaxf(mx.x, h.x); mx.y = fmaxf(mx.y, h.y);
            mx.z = fmaxf(mx.z, h.z); mx.w = fmaxf(mx.w, h.w);
            mn.x = fminf(mn.x, h.x); mn.y = fminf(mn.y, h.y);
            mn.z = fminf(mn.z, h.z); mn.w = fminf(mn.w, h.w);
            sum4.x += h.x; sum4.y += h.y; sum4.z += h.z; sum4.w += h.w;
            ssq4.x = fmaf(h.x, h.x, ssq4.x); ssq4.y = fmaf(h.y, h.y, ssq4.y);
            ssq4.z = fmaf(h.z, h.z, ssq4.z); ssq4.w = fmaf(h.w, h.w, ssq4.w);
        }
#pragma unroll
        for (int m = 16; m <= 32; m <<= 1) {
            mx.x = fmaxf(mx.x, __shfl_xor(mx.x, m));
            mx.y = fmaxf(mx.y, __shfl_xor(mx.y, m));
            mx.z = fmaxf(mx.z, __shfl_xor(mx.z, m));
            mx.w = fmaxf(mx.w, __shfl_xor(mx.w, m));
            mn.x = fminf(mn.x, __shfl_xor(mn.x, m));
            mn.y = fminf(mn.y, __shfl_xor(mn.y, m));
            mn.z = fminf(mn.z, __shfl_xor(mn.z, m));
            mn.w = fminf(mn.w, __shfl_xor(mn.w, m));
        }
        if (g < 2) {
            float4 v = (g == 0) ? mx : mn;
            __half2 pa = __floats2half2_rn(v.x, v.y);
            __half2 pb = __floats2half2_rn(v.z, v.w);
            uint2 pk;
            pk.x = *reinterpret_cast<unsigned*>(&pa);
            pk.y = *reinterpret_cast<unsigned*>(&pb);
            *reinterpret_cast<uint2*>(hmm + ((size_t)b * NN + n) * 128 + g * 64 + 4 * q) = pk;
        }
    }

#pragma unroll
    for (int m = 16; m <= 32; m <<= 1) {
        sum4.x += __shfl_xor(sum4.x, m); sum4.y += __shfl_xor(sum4.y, m);
        sum4.z += __shfl_xor(sum4.z, m); sum4.w += __shfl_xor(sum4.w, m);
        ssq4.x += __shfl_xor(ssq4.x, m); ssq4.y += __shfl_xor(ssq4.y, m);
        ssq4.z += __shfl_xor(ssq4.z, m); ssq4.w += __shfl_xor(ssq4.w, m);
    }
    __shared__ float rs[4][64], rq[4][64];
    if (g == 0) {
        *reinterpret_cast<float4*>(&rs[w][4 * q]) = sum4;
        *reinterpret_cast<float4*>(&rq[w][4 * q]) = ssq4;
    }
    __syncthreads();
    if (w == 0) {
        float s = rs[0][lane] + rs[1][lane] + rs[2][lane] + rs[3][lane];
        float qq = rq[0][lane] + rq[1][lane] + rq[2][lane] + rq[3][lane];
        psum[(size_t)blockIdx.x * 64 + lane] = s;
        pssq[(size_t)blockIdx.x * 64 + lane] = qq;
    }
}

// ---------------------------------------------------------------------------
// Pass 2b stage 1: 32 blocks reduce the 2048 partial rows.
// ---------------------------------------------------------------------------
__global__ __launch_bounds__(256) void pass2b_stage1(const float* __restrict__ psum,
                                                     const float* __restrict__ pssq,
                                                     double* __restrict__ p2sum,
                                                     double* __restrict__ p2ssq,
                                                     int nblocks) {
    const int t = threadIdx.x;
    const int c = t & 63, s = t >> 6;
    double sum = 0.0, ssq = 0.0;
    for (int i = blockIdx.x * 4 + s; i < nblocks; i += 32 * 4) {
        sum += (double)psum[(size_t)i * 64 + c];
        ssq += (double)pssq[(size_t)i * 64 + c];
    }
    __shared__ double ds_[4][64], dq_[4][64];
    ds_[s][c] = sum;
    dq_[s][c] = ssq;
    __syncthreads();
    if (s == 0) {
        p2sum[(size_t)blockIdx.x * 64 + c] = ds_[0][c] + ds_[1][c] + ds_[2][c] + ds_[3][c];
        p2ssq[(size_t)blockIdx.x * 64 + c] = dq_[0][c] + dq_[1][c] + dq_[2][c] + dq_[3][c];
    }
}

// ---------------------------------------------------------------------------
// Pass 2b stage 2: single block -> scale/shift.
// ---------------------------------------------------------------------------
__global__ __launch_bounds__(256) void pass2b_stage2(const double* __restrict__ p2sum,
                                                     const double* __restrict__ p2ssq,
                                                     const float* __restrict__ gamma,
                                                     const float* __restrict__ beta,
                                                     float* __restrict__ scsh) {
    const int t = threadIdx.x;
    const int c = t & 63, s = t >> 6;
    double sum = 0.0, ssq = 0.0;
    for (int i = s; i < 32; i += 4) {
        sum += p2sum[(size_t)i * 64 + c];
        ssq += p2ssq[(size_t)i * 64 + c];
    }
    __shared__ double ds_[4][64], dq_[4][64];
    ds_[s][c] = sum;
    dq_[s][c] = ssq;
    __syncthreads();
    if (s == 0) {
        double S = ds_[0][c] + ds_[1][c] + ds_[2][c] + ds_[3][c];
        double Q = dq_[0][c] + dq_[1][c] + dq_[2][c] + dq_[3][c];
        const double cnt = (double)BB * NN * KK;
        double mean = S / cnt;
        double var  = Q / cnt - mean * mean;
        float scale = (float)((double)gamma[c] / sqrt(var + BN_EPS));
        float shift = (float)((double)beta[c] - mean * (double)scale);
        scsh[c]      = scale;
        scsh[64 + c] = shift;
    }
}

// ---------------------------------------------------------------------------
// Pass 4: out[b][o][n] = relu(scale[o]*hsel + shift[o]); hmm rows are fp16.
// ---------------------------------------------------------------------------
__global__ __launch_bounds__(256) void pass4_out(const __half* __restrict__ hmm,
                                                 const float* __restrict__ scsh,
                                                 float* __restrict__ out) {
    const int b  = blockIdx.x & 7;
    const int n0 = (blockIdx.x >> 3) * 64;
    const int w    = threadIdx.x >> 6;
    const int lane = threadIdx.x & 63;

    __shared__ float ts[64][65];
    const float sc = scsh[lane];
    const float sh = scsh[64 + lane];

    for (int i = 0; i < 16; ++i) {
        const int j = w + 4 * i;
        const __half* row = hmm + ((size_t)b * NN + n0 + j) * 128;
        float hv = (sc >= 0.f) ? __half2float(row[lane])
                               : __half2float(row[64 + lane]);
        ts[j][lane] = fmaxf(0.f, fmaf(sc, hv, sh));
    }
    __syncthreads();
    for (int i = 0; i < 16; ++i) {
        const int o = w + 4 * i;
        out[((size_t)b * COUT + o) * NN + n0 + lane] = ts[lane][o];
    }
}

// ---------------------------------------------------------------------------
extern "C" void kernel_launch(void* const* d_in, const int* in_sizes, int n_in,
                              void* d_out, int out_size, void* d_ws, size_t ws_size,
                              hipStream_t stream) {
    const float* x     = (const float*)d_in[0]; // [B, C, N, 1]
    const float* wgt   = (const float*)d_in[1]; // [64, 128]
    const float* gamma = (const float*)d_in[2]; // [64]
    const float* beta  = (const float*)d_in[3]; // [64]
    const int*   eidx  = (const int*)d_in[4];   // [2, B, N, K]
    float* out = (float*)d_out;                 // [B, 64, N]

    // workspace layout
    float*  yc   = (float*)d_ws;                          // B*N*128 floats (32 MB)
    __half* hmm  = (__half*)(yc + (size_t)BB * NN * 128); // B*N*128 halves (16 MB)
    float*  psum = (float*)(hmm + (size_t)BB * NN * 128); // 2048*64 floats
    float*  pssq = psum + (size_t)(BB * (NN / 32)) * 64;  // 2048*64 floats
    float*  scsh = pssq + (size_t)(BB * (NN / 32)) * 64;  // 128 floats
    double* p2sum = (double*)(scsh + 128 + 32);           // 32*64 doubles
    double* p2ssq = p2sum + 32 * 64;                      // 32*64 doubles
    float*  wt    = (float*)(p2ssq + 32 * 64);            // 64*128 floats (32 KB)

    const int nblk2 = BB * (NN / 32); // 2048

    hipLaunchKernelGGL(pass0_wt, dim3(1), dim3(256), 0, stream, wgt, wt);
    hipLaunchKernelGGL(pass1_yc, dim3(BB * (NN / 64)), dim3(256), 0, stream,
                       x, wt, yc);
    hipLaunchKernelGGL(pass2_gather, dim3(nblk2), dim3(256), 0, stream,
                       yc, eidx, hmm, psum, pssq);
    hipLaunchKernelGGL(pass2b_stage1, dim3(32), dim3(256), 0, stream,
                       psum, pssq, p2sum, p2ssq, nblk2);
    hipLaunchKernelGGL(pass2b_stage2, dim3(1), dim3(256), 0, stream,
                       p2sum, p2ssq, gamma, beta, scsh);
    hipLaunchKernelGGL(pass4_out, dim3(BB * (NN / 64)), dim3(256), 0, stream,
                       hmm, scsh, out);
}

// Round 10
// 82.954 us; speedup vs baseline: 1.5077x; 1.5077x over previous
//
#include <hip/hip_runtime.h>
#include <hip/hip_fp16.h>
#include <math.h>

#define BB 8
#define CC 64
#define NN 8192
#define KK 20
#define COUT 64
#define BN_EPS 1e-5

typedef _Float16 f16x8 __attribute__((ext_vector_type(8)));
typedef _Float16 f16x4 __attribute__((ext_vector_type(4)));
typedef float f32x4 __attribute__((ext_vector_type(4)));

// XCD swizzle: blockIdx round-robins over 8 XCDs -> (blockIdx.x & 7) == XCD.
// Batch b pinned to XCD b keeps b's yc/xT slices resident in that XCD's L2.

// ---------------------------------------------------------------------------
// Pass 0w: wtT[o2][c] fp16, c-contiguous (one 16B load per MFMA B-fragment):
//   o2 <  64: wa[o2][c] = w[o2][c] - w[o2][64+c]
//   o2 >= 64: wb[o2-64][c] = w[o2-64][64+c]
// ---------------------------------------------------------------------------
__global__ __launch_bounds__(256) void pass0_wt(const float* __restrict__ w,
                                                _Float16* __restrict__ wtT) {
    for (int idx = threadIdx.x; idx < 128 * 64; idx += 256) {
        const int o2 = idx >> 6;
        const int c  = idx & 63;
        float v;
        if (o2 < 64) v = w[o2 * 128 + c] - w[o2 * 128 + 64 + c];
        else         v = w[(o2 - 64) * 128 + 64 + c];
        wtT[idx] = (_Float16)v;
    }
}

// ---------------------------------------------------------------------------
// Pass 0x: x f32 [b][c][n] -> xT fp16 [b][n][c] (A-fragment = one 16B load).
// LDS-tiled 64x64 transpose; f32 tile padded [64][65] (conflict-free).
// ---------------------------------------------------------------------------
__global__ __launch_bounds__(256) void pass0_xt(const float* __restrict__ x,
                                                _Float16* __restrict__ xT) {
    const int b  = blockIdx.x & 7;
    const int n0 = (blockIdx.x >> 3) * 64;
    const int t  = threadIdx.x;
    const int wv   = t >> 6;
    const int lane = t & 63;

    __shared__ float T[64][65];

    for (int c = wv; c < 64; c += 4)
        T[c][lane] = x[((size_t)b * CC + c) * NN + n0 + lane];
    __syncthreads();

    const int part = t >> 6;   // c-range part*16..+16
    const int n    = t & 63;
    union { _Float16 h[16]; uint4 u[2]; } pk;
#pragma unroll
    for (int cc = 0; cc < 16; ++cc)
        pk.h[cc] = (_Float16)T[part * 16 + cc][n];   // bank (c+n)%32: conflict-free
    uint4* dst = reinterpret_cast<uint4*>(xT + ((size_t)b * NN + n0 + n) * 64 + part * 16);
    dst[0] = pk.u[0];
    dst[1] = pk.u[1];
}

// ---------------------------------------------------------------------------
// Pass 1 (MFMA): yc[b][n][o2] fp16 = sum_c xT[b][n][c] * wtT[o2][c].
// Block = 64 n x 128 o2; wave = 16 n strip. mfma_f32_16x16x32_f16:
//   A lane l: row n = l&15, k = (l>>4)*8 + j  (one f16x8 = 16B from xT)
//   B lane l: col o = l&15, k = (l>>4)*8 + j  (one f16x8 = 16B from wtT)
//   D lane l: col = l&15, row = (l>>4)*4 + r  [verified layout, m89]
// No LDS; 18 VMEM + 16 MFMA per wave; memory-bound on the 16 MB yc write.
// ---------------------------------------------------------------------------
__global__ __launch_bounds__(256) void pass1_mfma(const _Float16* __restrict__ xT,
                                                  const _Float16* __restrict__ wtT,
                                                  _Float16* __restrict__ yc) {
    const int blk = blockIdx.x;            // 1024 blocks
    const int b   = blk & 7;
    const int ng  = blk >> 3;              // 0..127
    const int wv  = __builtin_amdgcn_readfirstlane(threadIdx.x >> 6);
    const int lane = threadIdx.x & 63;
    const int n0  = ng * 64 + wv * 16;     // wave's 16-n strip
    const int lr  = lane & 15;
    const int lg  = lane >> 4;

    // A-fragments (k = 0..31 and 32..63)
    const _Float16* xb = xT + ((size_t)b * NN + n0 + lr) * 64 + lg * 8;
    const f16x8 a0 = *reinterpret_cast<const f16x8*>(xb);
    const f16x8 a1 = *reinterpret_cast<const f16x8*>(xb + 32);

    f32x4 acc[8];
#pragma unroll
    for (int ob = 0; ob < 8; ++ob) {
        const _Float16* wp = wtT + ((size_t)(ob * 16 + lr)) * 64 + lg * 8;
        const f16x8 b0 = *reinterpret_cast<const f16x8*>(wp);
        const f16x8 b1 = *reinterpret_cast<const f16x8*>(wp + 32);
        f32x4 c_ = {0.f, 0.f, 0.f, 0.f};
        c_ = __builtin_amdgcn_mfma_f32_16x16x32_f16(a0, b0, c_, 0, 0, 0);
        c_ = __builtin_amdgcn_mfma_f32_16x16x32_f16(a1, b1, c_, 0, 0, 0);
        acc[ob] = c_;
    }

    // store: yc[n0 + lg*4 + r][ob*16 + lr]
    _Float16* ybase = yc + ((size_t)b * NN + n0 + lg * 4) * 128 + lr;
#pragma unroll
    for (int ob = 0; ob < 8; ++ob)
#pragma unroll
        for (int r = 0; r < 4; ++r)
            ybase[(size_t)r * 128 + ob * 16] = (_Float16)acc[ob][r];
}

// ---------------------------------------------------------------------------
// Pass 2 (fp16 gather): h[o] = yc[i1][o] + yc[i0][64+o], o-quad per lane.
// Lane layout: g = lane>>4 (k-slot), q = lane&15 (channel quad; 8B gathers).
// hmm fp16: row = [64 max][64 min].
// ---------------------------------------------------------------------------
__global__ __launch_bounds__(256, 6) void pass2_gather(const _Float16* __restrict__ yc,
                                                       const int* __restrict__ eidx,
                                                       __half* __restrict__ hmm,
                                                       float* __restrict__ psum,
                                                       float* __restrict__ pssq) {
    const int b  = blockIdx.x & 7;
    const int n0 = (blockIdx.x >> 3) * 32;
    const int w    = threadIdx.x >> 6;
    const int lane = threadIdx.x & 63;
    const int g = lane >> 4;
    const int q = lane & 15;

    const int* e0 = eidx + (size_t)b * NN * KK;
    const int* e1 = e0 + (size_t)BB * NN * KK;
    const _Float16* yca = yc + (size_t)b * NN * 128 + 4 * q;        // wa cols
    const _Float16* ycb = yca + 64;                                  // wb cols

    float4 sum4 = {0.f, 0.f, 0.f, 0.f};
    float4 ssq4 = {0.f, 0.f, 0.f, 0.f};

    for (int i = 0; i < 8; ++i) {
        const int n = n0 + w * 8 + i;
        const int* r1 = e1 + (size_t)n * KK;
        const int* r0 = e0 + (size_t)n * KK;
        int i1k[5], i0k[5];
#pragma unroll
        for (int s = 0; s < 5; ++s) {
            i1k[s] = r1[4 * s + g];
            i0k[s] = r0[4 * s + g];
        }
        float4 mx = {-3.402823466e38f, -3.402823466e38f, -3.402823466e38f, -3.402823466e38f};
        float4 mn = { 3.402823466e38f,  3.402823466e38f,  3.402823466e38f,  3.402823466e38f};
#pragma unroll
        for (int s = 0; s < 5; ++s) {
            f16x4 v1 = *reinterpret_cast<const f16x4*>(yca + (size_t)i1k[s] * 128);
            f16x4 v0 = *reinterpret_cast<const f16x4*>(ycb + (size_t)i0k[s] * 128);
            float4 h;
            h.x = (float)v1[0] + (float)v0[0];
            h.y = (float)v1[1] + (float)v0[1];
            h.z = (float)v1[2] + (float)v0[2];
            h.w = (float)v1[3] + (float)v0[3];
            mx.x = fmaxf(mx.x, h.x); mx.y = fmaxf(mx.y, h.y);
            mx.z = fmaxf(mx.z, h.z); mx.w = fmaxf(mx.w, h.w);
            mn.x = fminf(mn.x, h.x); mn.y = fminf(mn.y, h.y);
            mn.z = fminf(mn.z, h.z); mn.w = fminf(mn.w, h.w);
            sum4.x += h.x; sum4.y += h.y; sum4.z += h.z; sum4.w += h.w;
            ssq4.x = fmaf(h.x, h.x, ssq4.x); ssq4.y = fmaf(h.y, h.y, ssq4.y);
            ssq4.z = fmaf(h.z, h.z, ssq4.z); ssq4.w = fmaf(h.w, h.w, ssq4.w);
        }
#pragma unroll
        for (int m = 16; m <= 32; m <<= 1) {
            mx.x = fmaxf(mx.x, __shfl_xor(mx.x, m));
            mx.y = fmaxf(mx.y, __shfl_xor(mx.y, m));
            mx.z = fmaxf(mx.z, __shfl_xor(mx.z, m));
            mx.w = fmaxf(mx.w, __shfl_xor(mx.w, m));
            mn.x = fminf(mn.x, __shfl_xor(mn.x, m));
            mn.y = fminf(mn.y, __shfl_xor(mn.y, m));
            mn.z = fminf(mn.z, __shfl_xor(mn.z, m));
            mn.w = fminf(mn.w, __shfl_xor(mn.w, m));
        }
        if (g < 2) {
            float4 v = (g == 0) ? mx : mn;
            __half2 pa = __floats2half2_rn(v.x, v.y);
            __half2 pb = __floats2half2_rn(v.z, v.w);
            uint2 pk;
            pk.x = *reinterpret_cast<unsigned*>(&pa);
            pk.y = *reinterpret_cast<unsigned*>(&pb);
            *reinterpret_cast<uint2*>(hmm + ((size_t)b * NN + n) * 128 + g * 64 + 4 * q) = pk;
        }
    }

#pragma unroll
    for (int m = 16; m <= 32; m <<= 1) {
        sum4.x += __shfl_xor(sum4.x, m); sum4.y += __shfl_xor(sum4.y, m);
        sum4.z += __shfl_xor(sum4.z, m); sum4.w += __shfl_xor(sum4.w, m);
        ssq4.x += __shfl_xor(ssq4.x, m); ssq4.y += __shfl_xor(ssq4.y, m);
        ssq4.z += __shfl_xor(ssq4.z, m); ssq4.w += __shfl_xor(ssq4.w, m);
    }
    __shared__ float rs[4][64], rq[4][64];
    if (g == 0) {
        *reinterpret_cast<float4*>(&rs[w][4 * q]) = sum4;
        *reinterpret_cast<float4*>(&rq[w][4 * q]) = ssq4;
    }
    __syncthreads();
    if (w == 0) {
        float s = rs[0][lane] + rs[1][lane] + rs[2][lane] + rs[3][lane];
        float qq = rq[0][lane] + rq[1][lane] + rq[2][lane] + rq[3][lane];
        psum[(size_t)blockIdx.x * 64 + lane] = s;
        pssq[(size_t)blockIdx.x * 64 + lane] = qq;
    }
}

// ---------------------------------------------------------------------------
// Pass 2b stage 1: 32 blocks reduce the 2048 partial rows.
// ---------------------------------------------------------------------------
__global__ __launch_bounds__(256) void pass2b_stage1(const float* __restrict__ psum,
                                                     const float* __restrict__ pssq,
                                                     double* __restrict__ p2sum,
                                                     double* __restrict__ p2ssq,
                                                     int nblocks) {
    const int t = threadIdx.x;
    const int c = t & 63, s = t >> 6;
    double sum = 0.0, ssq = 0.0;
    for (int i = blockIdx.x * 4 + s; i < nblocks; i += 32 * 4) {
        sum += (double)psum[(size_t)i * 64 + c];
        ssq += (double)pssq[(size_t)i * 64 + c];
    }
    __shared__ double ds_[4][64], dq_[4][64];
    ds_[s][c] = sum;
    dq_[s][c] = ssq;
    __syncthreads();
    if (s == 0) {
        p2sum[(size_t)blockIdx.x * 64 + c] = ds_[0][c] + ds_[1][c] + ds_[2][c] + ds_[3][c];
        p2ssq[(size_t)blockIdx.x * 64 + c] = dq_[0][c] + dq_[1][c] + dq_[2][c] + dq_[3][c];
    }
}

// ---------------------------------------------------------------------------
// Pass 2b stage 2: single block -> scale/shift.
// ---------------------------------------------------------------------------
__global__ __launch_bounds__(256) void pass2b_stage2(const double* __restrict__ p2sum,
                                                     const double* __restrict__ p2ssq,
                                                     const float* __restrict__ gamma,
                                                     const float* __restrict__ beta,
                                                     float* __restrict__ scsh) {
    const int t = threadIdx.x;
    const int c = t & 63, s = t >> 6;
    double sum = 0.0, ssq = 0.0;
    for (int i = s; i < 32; i += 4) {
        sum += p2sum[(size_t)i * 64 + c];
        ssq += p2ssq[(size_t)i * 64 + c];
    }
    __shared__ double ds_[4][64], dq_[4][64];
    ds_[s][c] = sum;
    dq_[s][c] = ssq;
    __syncthreads();
    if (s == 0) {
        double S = ds_[0][c] + ds_[1][c] + ds_[2][c] + ds_[3][c];
        double Q = dq_[0][c] + dq_[1][c] + dq_[2][c] + dq_[3][c];
        const double cnt = (double)BB * NN * KK;
        double mean = S / cnt;
        double var  = Q / cnt - mean * mean;
        float scale = (float)((double)gamma[c] / sqrt(var + BN_EPS));
        float shift = (float)((double)beta[c] - mean * (double)scale);
        scsh[c]      = scale;
        scsh[64 + c] = shift;
    }
}

// ---------------------------------------------------------------------------
// Pass 4: out[b][o][n] = relu(scale[o]*hsel + shift[o]); hmm rows are fp16.
// ---------------------------------------------------------------------------
__global__ __launch_bounds__(256) void pass4_out(const __half* __restrict__ hmm,
                                                 const float* __restrict__ scsh,
                                                 float* __restrict__ out) {
    const int b  = blockIdx.x & 7;
    const int n0 = (blockIdx.x >> 3) * 64;
    const int w    = threadIdx.x >> 6;
    const int lane = threadIdx.x & 63;

    __shared__ float ts[64][65];
    const float sc = scsh[lane];
    const float sh = scsh[64 + lane];

    for (int i = 0; i < 16; ++i) {
        const int j = w + 4 * i;
        const __half* row = hmm + ((size_t)b * NN + n0 + j) * 128;
        float hv = (sc >= 0.f) ? __half2float(row[lane])
                               : __half2float(row[64 + lane]);
        ts[j][lane] = fmaxf(0.f, fmaf(sc, hv, sh));
    }
    __syncthreads();
    for (int i = 0; i < 16; ++i) {
        const int o = w + 4 * i;
        out[((size_t)b * COUT + o) * NN + n0 + lane] = ts[lane][o];
    }
}

// ---------------------------------------------------------------------------
extern "C" void kernel_launch(void* const* d_in, const int* in_sizes, int n_in,
                              void* d_out, int out_size, void* d_ws, size_t ws_size,
                              hipStream_t stream) {
    const float* x     = (const float*)d_in[0]; // [B, C, N, 1]
    const float* wgt   = (const float*)d_in[1]; // [64, 128]
    const float* gamma = (const float*)d_in[2]; // [64]
    const float* beta  = (const float*)d_in[3]; // [64]
    const int*   eidx  = (const int*)d_in[4];   // [2, B, N, K]
    float* out = (float*)d_out;                 // [B, 64, N]

    // workspace layout
    _Float16* yc  = (_Float16*)d_ws;                      // B*N*128 fp16 (16 MB)
    _Float16* xT  = yc + (size_t)BB * NN * 128;           // B*N*64  fp16 ( 8 MB)
    __half*   hmm = (__half*)(xT + (size_t)BB * NN * 64); // B*N*128 fp16 (16 MB)
    float*  psum  = (float*)(hmm + (size_t)BB * NN * 128);// 2048*64 f32
    float*  pssq  = psum + (size_t)2048 * 64;
    double* p2sum = (double*)(pssq + (size_t)2048 * 64);  // 32*64 f64
    double* p2ssq = p2sum + 32 * 64;
    float*  scsh  = (float*)(p2ssq + 32 * 64);            // 128 f32
    _Float16* wtT = (_Float16*)(scsh + 128);              // 128*64 fp16 (16 KB)

    const int nblk2 = BB * (NN / 32); // 2048

    hipLaunchKernelGGL(pass0_wt, dim3(1), dim3(256), 0, stream, wgt, wtT);
    hipLaunchKernelGGL(pass0_xt, dim3(BB * (NN / 64)), dim3(256), 0, stream,
                       x, xT);
    hipLaunchKernelGGL(pass1_mfma, dim3(BB * (NN / 64)), dim3(256), 0, stream,
                       xT, wtT, yc);
    hipLaunchKernelGGL(pass2_gather, dim3(nblk2), dim3(256), 0, stream,
                       yc, eidx, hmm, psum, pssq);
    hipLaunchKernelGGL(pass2b_stage1, dim3(32), dim3(256), 0, stream,
                       psum, pssq, p2sum, p2ssq, nblk2);
    hipLaunchKernelGGL(pass2b_stage2, dim3(1), dim3(256), 0, stream,
                       p2sum, p2ssq, gamma, beta, scsh);
    hipLaunchKernelGGL(pass4_out, dim3(BB * (NN / 64)), dim3(256), 0, stream,
                       hmm, scsh, out);
}

// Round 11
// 78.529 us; speedup vs baseline: 1.5927x; 1.0563x over previous
//
#include <hip/hip_runtime.h>
#include <hip/hip_fp16.h>
#include <math.h>

#define BB 8
#define CC 64
#define NN 8192
#define KK 20
#define COUT 64
#define BN_EPS 1e-5

typedef _Float16 f16x8 __attribute__((ext_vector_type(8)));
typedef _Float16 f16x4 __attribute__((ext_vector_type(4)));
typedef float f32x4 __attribute__((ext_vector_type(4)));

// XCD swizzle: blockIdx round-robins over 8 XCDs -> (blockIdx.x & 7) == XCD.
// Batch b pinned to XCD b keeps b's yc/xT slices resident in that XCD's L2.

// ---------------------------------------------------------------------------
// Pass 0w: wtT[o2][c] fp16, c-contiguous (one 16B load per MFMA B-fragment).
// ---------------------------------------------------------------------------
__global__ __launch_bounds__(256) void pass0_wt(const float* __restrict__ w,
                                                _Float16* __restrict__ wtT) {
    for (int idx = threadIdx.x; idx < 128 * 64; idx += 256) {
        const int o2 = idx >> 6;
        const int c  = idx & 63;
        float v;
        if (o2 < 64) v = w[o2 * 128 + c] - w[o2 * 128 + 64 + c];
        else         v = w[(o2 - 64) * 128 + 64 + c];
        wtT[idx] = (_Float16)v;
    }
}

// ---------------------------------------------------------------------------
// Pass 0x: x f32 [b][c][n] -> xT fp16 [b][n][c] via LDS-tiled transpose.
// ---------------------------------------------------------------------------
__global__ __launch_bounds__(256) void pass0_xt(const float* __restrict__ x,
                                                _Float16* __restrict__ xT) {
    const int b  = blockIdx.x & 7;
    const int n0 = (blockIdx.x >> 3) * 64;
    const int t  = threadIdx.x;
    const int wv   = t >> 6;
    const int lane = t & 63;

    __shared__ float T[64][65];

    for (int c = wv; c < 64; c += 4)
        T[c][lane] = x[((size_t)b * CC + c) * NN + n0 + lane];
    __syncthreads();

    const int part = t >> 6;
    const int n    = t & 63;
    union { _Float16 h[16]; uint4 u[2]; } pk;
#pragma unroll
    for (int cc = 0; cc < 16; ++cc)
        pk.h[cc] = (_Float16)T[part * 16 + cc][n];
    uint4* dst = reinterpret_cast<uint4*>(xT + ((size_t)b * NN + n0 + n) * 64 + part * 16);
    dst[0] = pk.u[0];
    dst[1] = pk.u[1];
}

// ---------------------------------------------------------------------------
// Pass 1 (MFMA): yc[b][n][o2] fp16 = sum_c xT[b][n][c] * wtT[o2][c].
// ---------------------------------------------------------------------------
__global__ __launch_bounds__(256) void pass1_mfma(const _Float16* __restrict__ xT,
                                                  const _Float16* __restrict__ wtT,
                                                  _Float16* __restrict__ yc) {
    const int blk = blockIdx.x;
    const int b   = blk & 7;
    const int ng  = blk >> 3;
    const int wv  = __builtin_amdgcn_readfirstlane(threadIdx.x >> 6);
    const int lane = threadIdx.x & 63;
    const int n0  = ng * 64 + wv * 16;
    const int lr  = lane & 15;
    const int lg  = lane >> 4;

    const _Float16* xb = xT + ((size_t)b * NN + n0 + lr) * 64 + lg * 8;
    const f16x8 a0 = *reinterpret_cast<const f16x8*>(xb);
    const f16x8 a1 = *reinterpret_cast<const f16x8*>(xb + 32);

    f32x4 acc[8];
#pragma unroll
    for (int ob = 0; ob < 8; ++ob) {
        const _Float16* wp = wtT + ((size_t)(ob * 16 + lr)) * 64 + lg * 8;
        const f16x8 b0 = *reinterpret_cast<const f16x8*>(wp);
        const f16x8 b1 = *reinterpret_cast<const f16x8*>(wp + 32);
        f32x4 c_ = {0.f, 0.f, 0.f, 0.f};
        c_ = __builtin_amdgcn_mfma_f32_16x16x32_f16(a0, b0, c_, 0, 0, 0);
        c_ = __builtin_amdgcn_mfma_f32_16x16x32_f16(a1, b1, c_, 0, 0, 0);
        acc[ob] = c_;
    }

    _Float16* ybase = yc + ((size_t)b * NN + n0 + lg * 4) * 128 + lr;
#pragma unroll
    for (int ob = 0; ob < 8; ++ob)
#pragma unroll
        for (int r = 0; r < 4; ++r)
            ybase[(size_t)r * 128 + ob * 16] = (_Float16)acc[ob][r];
}

// ---------------------------------------------------------------------------
// Pass 2 (lane-per-n layout, no per-n cross-lane ops):
// lane = (nsub = lane>>4, q = lane&15). Each lane owns n = base + nsub and
// channel quad q, iterating ALL 20 k: max/min accumulate per-lane in packed
// fp16 (v_pk_max/min), sum/ssq in f32. 40 indices preloaded -> 40 independent
// 8B gathers in one vmcnt queue. Cross-lane reduce only once per wave (sum).
// hmm fp16 row = [64 max][64 min].
// ---------------------------------------------------------------------------
__global__ __launch_bounds__(256, 4) void pass2_gather(const _Float16* __restrict__ yc,
                                                       const int* __restrict__ eidx,
                                                       __half* __restrict__ hmm,
                                                       float* __restrict__ psum,
                                                       float* __restrict__ pssq) {
    const int b  = blockIdx.x & 7;
    const int n0 = (blockIdx.x >> 3) * 32;
    const int w    = threadIdx.x >> 6;
    const int lane = threadIdx.x & 63;
    const int nsub = lane >> 4;   // which of 4 n this lane owns
    const int q    = lane & 15;   // channel quad

    const int* e0 = eidx + (size_t)b * NN * KK;
    const int* e1 = e0 + (size_t)BB * NN * KK;
    const _Float16* yca = yc + (size_t)b * NN * 128 + 4 * q;   // wa cols
    const _Float16* ycb = yca + 64;                             // wb cols

    float4 sum4 = {0.f, 0.f, 0.f, 0.f};
    float4 ssq4 = {0.f, 0.f, 0.f, 0.f};

    for (int it = 0; it < 2; ++it) {
        const int n = n0 + w * 8 + it * 4 + nsub;
        // preload this lane's 40 indices (10 x int4, rows 16B-aligned: 80|n*80)
        const int4* p1 = reinterpret_cast<const int4*>(e1 + (size_t)n * KK);
        const int4* p0 = reinterpret_cast<const int4*>(e0 + (size_t)n * KK);
        int i1k[20], i0k[20];
#pragma unroll
        for (int c4 = 0; c4 < 5; ++c4) {
            int4 a = p1[c4];
            i1k[4 * c4 + 0] = a.x; i1k[4 * c4 + 1] = a.y;
            i1k[4 * c4 + 2] = a.z; i1k[4 * c4 + 3] = a.w;
            int4 c = p0[c4];
            i0k[4 * c4 + 0] = c.x; i0k[4 * c4 + 1] = c.y;
            i0k[4 * c4 + 2] = c.z; i0k[4 * c4 + 3] = c.w;
        }

        f16x4 hmx = {(_Float16)-65504.f, (_Float16)-65504.f,
                     (_Float16)-65504.f, (_Float16)-65504.f};
        f16x4 hmn = {(_Float16)65504.f, (_Float16)65504.f,
                     (_Float16)65504.f, (_Float16)65504.f};
#pragma unroll
        for (int k = 0; k < KK; ++k) {
            f16x4 v1 = *reinterpret_cast<const f16x4*>(yca + (size_t)i1k[k] * 128);
            f16x4 v0 = *reinterpret_cast<const f16x4*>(ycb + (size_t)i0k[k] * 128);
            f16x4 h = v1 + v0;                       // v_pk_add_f16
            hmx = __builtin_elementwise_max(hmx, h); // v_pk_max_f16
            hmn = __builtin_elementwise_min(hmn, h);
            float h0 = (float)h[0], h1 = (float)h[1];
            float h2 = (float)h[2], h3 = (float)h[3];
            sum4.x += h0; sum4.y += h1; sum4.z += h2; sum4.w += h3;
            ssq4.x = fmaf(h0, h0, ssq4.x); ssq4.y = fmaf(h1, h1, ssq4.y);
            ssq4.z = fmaf(h2, h2, ssq4.z); ssq4.w = fmaf(h3, h3, ssq4.w);
        }
        // store max/min quads (fp16, no conversion): 128B segment per nsub
        union { f16x4 v; uint2 u; } px, pn;
        px.v = hmx; pn.v = hmn;
        __half* row = hmm + ((size_t)b * NN + n) * 128;
        *reinterpret_cast<uint2*>(row + 4 * q)      = px.u;
        *reinterpret_cast<uint2*>(row + 64 + 4 * q) = pn.u;
    }

    // cross-lane sum/ssq reduce over nsub (once per wave)
#pragma unroll
    for (int m = 16; m <= 32; m <<= 1) {
        sum4.x += __shfl_xor(sum4.x, m); sum4.y += __shfl_xor(sum4.y, m);
        sum4.z += __shfl_xor(sum4.z, m); sum4.w += __shfl_xor(sum4.w, m);
        ssq4.x += __shfl_xor(ssq4.x, m); ssq4.y += __shfl_xor(ssq4.y, m);
        ssq4.z += __shfl_xor(ssq4.z, m); ssq4.w += __shfl_xor(ssq4.w, m);
    }
    __shared__ float rs[4][64], rq[4][64];
    if (nsub == 0) {
        *reinterpret_cast<float4*>(&rs[w][4 * q]) = sum4;
        *reinterpret_cast<float4*>(&rq[w][4 * q]) = ssq4;
    }
    __syncthreads();
    if (w == 0) {
        float s = rs[0][lane] + rs[1][lane] + rs[2][lane] + rs[3][lane];
        float qq = rq[0][lane] + rq[1][lane] + rq[2][lane] + rq[3][lane];
        psum[(size_t)blockIdx.x * 64 + lane] = s;
        pssq[(size_t)blockIdx.x * 64 + lane] = qq;
    }
}

// ---------------------------------------------------------------------------
// Pass 2b stage 1: 32 blocks reduce the 2048 partial rows.
// ---------------------------------------------------------------------------
__global__ __launch_bounds__(256) void pass2b_stage1(const float* __restrict__ psum,
                                                     const float* __restrict__ pssq,
                                                     double* __restrict__ p2sum,
                                                     double* __restrict__ p2ssq,
                                                     int nblocks) {
    const int t = threadIdx.x;
    const int c = t & 63, s = t >> 6;
    double sum = 0.0, ssq = 0.0;
    for (int i = blockIdx.x * 4 + s; i < nblocks; i += 32 * 4) {
        sum += (double)psum[(size_t)i * 64 + c];
        ssq += (double)pssq[(size_t)i * 64 + c];
    }
    __shared__ double ds_[4][64], dq_[4][64];
    ds_[s][c] = sum;
    dq_[s][c] = ssq;
    __syncthreads();
    if (s == 0) {
        p2sum[(size_t)blockIdx.x * 64 + c] = ds_[0][c] + ds_[1][c] + ds_[2][c] + ds_[3][c];
        p2ssq[(size_t)blockIdx.x * 64 + c] = dq_[0][c] + dq_[1][c] + dq_[2][c] + dq_[3][c];
    }
}

// ---------------------------------------------------------------------------
// Pass 2b stage 2: single block -> scale/shift.
// ---------------------------------------------------------------------------
__global__ __launch_bounds__(256) void pass2b_stage2(const double* __restrict__ p2sum,
                                                     const double* __restrict__ p2ssq,
                                                     const float* __restrict__ gamma,
                                                     const float* __restrict__ beta,
                                                     float* __restrict__ scsh) {
    const int t = threadIdx.x;
    const int c = t & 63, s = t >> 6;
    double sum = 0.0, ssq = 0.0;
    for (int i = s; i < 32; i += 4) {
        sum += p2sum[(size_t)i * 64 + c];
        ssq += p2ssq[(size_t)i * 64 + c];
    }
    __shared__ double ds_[4][64], dq_[4][64];
    ds_[s][c] = sum;
    dq_[s][c] = ssq;
    __syncthreads();
    if (s == 0) {
        double S = ds_[0][c] + ds_[1][c] + ds_[2][c] + ds_[3][c];
        double Q = dq_[0][c] + dq_[1][c] + dq_[2][c] + dq_[3][c];
        const double cnt = (double)BB * NN * KK;
        double mean = S / cnt;
        double var  = Q / cnt - mean * mean;
        float scale = (float)((double)gamma[c] / sqrt(var + BN_EPS));
        float shift = (float)((double)beta[c] - mean * (double)scale);
        scsh[c]      = scale;
        scsh[64 + c] = shift;
    }
}

// ---------------------------------------------------------------------------
// Pass 4: out[b][o][n] = relu(scale[o]*hsel + shift[o]); hmm rows are fp16.
// ---------------------------------------------------------------------------
__global__ __launch_bounds__(256) void pass4_out(const __half* __restrict__ hmm,
                                                 const float* __restrict__ scsh,
                                                 float* __restrict__ out) {
    const int b  = blockIdx.x & 7;
    const int n0 = (blockIdx.x >> 3) * 64;
    const int w    = threadIdx.x >> 6;
    const int lane = threadIdx.x & 63;

    __shared__ float ts[64][65];
    const float sc = scsh[lane];
    const float sh = scsh[64 + lane];

    for (int i = 0; i < 16; ++i) {
        const int j = w + 4 * i;
        const __half* row = hmm + ((size_t)b * NN + n0 + j) * 128;
        float hv = (sc >= 0.f) ? __half2float(row[lane])
                               : __half2float(row[64 + lane]);
        ts[j][lane] = fmaxf(0.f, fmaf(sc, hv, sh));
    }
    __syncthreads();
    for (int i = 0; i < 16; ++i) {
        const int o = w + 4 * i;
        out[((size_t)b * COUT + o) * NN + n0 + lane] = ts[lane][o];
    }
}

// ---------------------------------------------------------------------------
extern "C" void kernel_launch(void* const* d_in, const int* in_sizes, int n_in,
                              void* d_out, int out_size, void* d_ws, size_t ws_size,
                              hipStream_t stream) {
    const float* x     = (const float*)d_in[0]; // [B, C, N, 1]
    const float* wgt   = (const float*)d_in[1]; // [64, 128]
    const float* gamma = (const float*)d_in[2]; // [64]
    const float* beta  = (const float*)d_in[3]; // [64]
    const int*   eidx  = (const int*)d_in[4];   // [2, B, N, K]
    float* out = (float*)d_out;                 // [B, 64, N]

    // workspace layout
    _Float16* yc  = (_Float16*)d_ws;                      // B*N*128 fp16 (16 MB)
    _Float16* xT  = yc + (size_t)BB * NN * 128;           // B*N*64  fp16 ( 8 MB)
    __half*   hmm = (__half*)(xT + (size_t)BB * NN * 64); // B*N*128 fp16 (16 MB)
    float*  psum  = (float*)(hmm + (size_t)BB * NN * 128);// 2048*64 f32
    float*  pssq  = psum + (size_t)2048 * 64;
    double* p2sum = (double*)(pssq + (size_t)2048 * 64);  // 32*64 f64
    double* p2ssq = p2sum + 32 * 64;
    float*  scsh  = (float*)(p2ssq + 32 * 64);            // 128 f32
    _Float16* wtT = (_Float16*)(scsh + 128);              // 128*64 fp16 (16 KB)

    const int nblk2 = BB * (NN / 32); // 2048

    hipLaunchKernelGGL(pass0_wt, dim3(1), dim3(256), 0, stream, wgt, wtT);
    hipLaunchKernelGGL(pass0_xt, dim3(BB * (NN / 64)), dim3(256), 0, stream,
                       x, xT);
    hipLaunchKernelGGL(pass1_mfma, dim3(BB * (NN / 64)), dim3(256), 0, stream,
                       xT, wtT, yc);
    hipLaunchKernelGGL(pass2_gather, dim3(nblk2), dim3(256), 0, stream,
                       yc, eidx, hmm, psum, pssq);
    hipLaunchKernelGGL(pass2b_stage1, dim3(32), dim3(256), 0, stream,
                       psum, pssq, p2sum, p2ssq, nblk2);
    hipLaunchKernelGGL(pass2b_stage2, dim3(1), dim3(256), 0, stream,
                       p2sum, p2ssq, gamma, beta, scsh);
    hipLaunchKernelGGL(pass4_out, dim3(BB * (NN / 64)), dim3(256), 0, stream,
                       hmm, scsh, out);
}

// Round 12
// 68.654 us; speedup vs baseline: 1.8218x; 1.1438x over previous
//
#include <hip/hip_runtime.h>
#include <hip/hip_fp16.h>
#include <math.h>

#define BB 8
#define CC 64
#define NN 8192
#define KK 20
#define COUT 64
#define BN_EPS 1e-5

typedef _Float16 f16x8 __attribute__((ext_vector_type(8)));
typedef _Float16 f16x4 __attribute__((ext_vector_type(4)));
typedef float f32x4 __attribute__((ext_vector_type(4)));

// XCD swizzle: blockIdx round-robins over 8 XCDs -> (blockIdx.x & 7) == XCD.
// Batch b pinned to XCD b keeps b's yc slice resident in that XCD's L2.

// ---------------------------------------------------------------------------
// Pass 0w: wtT[o2][c] fp16, c-contiguous (one 16B load per MFMA B-fragment).
// 32 blocks x 256 threads = one element per thread.
// ---------------------------------------------------------------------------
__global__ __launch_bounds__(256) void pass0_wt(const float* __restrict__ w,
                                                _Float16* __restrict__ wtT) {
    const int idx = blockIdx.x * 256 + threadIdx.x;   // 8192 elements
    const int o2 = idx >> 6;
    const int c  = idx & 63;
    float v;
    if (o2 < 64) v = w[o2 * 128 + c] - w[o2 * 128 + 64 + c];
    else         v = w[(o2 - 64) * 128 + 64 + c];
    wtT[idx] = (_Float16)v;
}

// ---------------------------------------------------------------------------
// Pass 1 (fused transpose + MFMA): yc[b][n][o2] fp16 = sum_c x[b][c][n]*wt[o2][c].
// Stage x f32 tile [64 c][64 n] in LDS (coalesced), convert to fp16 fragments
// at read time (bank = (c + 16wv + lr)%32 -> 2-way, free). No xT round-trip.
//   A lane l: row n = l&15, k(c) = (l>>4)*8 + j
//   B lane l: col o = l&15, k(c) = (l>>4)*8 + j   (16B load from wtT)
//   D lane l: col = l&15, row = (l>>4)*4 + r      [verified layout, m89]
// ---------------------------------------------------------------------------
__global__ __launch_bounds__(256) void pass1_mfma(const float* __restrict__ x,
                                                  const _Float16* __restrict__ wtT,
                                                  _Float16* __restrict__ yc) {
    const int blk = blockIdx.x;            // 1024 blocks
    const int b   = blk & 7;
    const int ng  = blk >> 3;              // 0..127
    const int n0  = ng * 64;
    const int tid = threadIdx.x;
    const int wv  = __builtin_amdgcn_readfirstlane(tid >> 6);
    const int lane = tid & 63;

    __shared__ float T[64][65];            // T[c][n]

    for (int c = wv; c < 64; c += 4)
        T[c][lane] = x[((size_t)b * CC + c) * NN + n0 + lane];
    __syncthreads();

    const int lr = lane & 15;
    const int lg = lane >> 4;

    f16x8 a0, a1;
#pragma unroll
    for (int j = 0; j < 8; ++j) {
        a0[j] = (_Float16)T[lg * 8 + j][wv * 16 + lr];
        a1[j] = (_Float16)T[32 + lg * 8 + j][wv * 16 + lr];
    }

    f32x4 acc[8];
#pragma unroll
    for (int ob = 0; ob < 8; ++ob) {
        const _Float16* wp = wtT + ((size_t)(ob * 16 + lr)) * 64 + lg * 8;
        const f16x8 b0 = *reinterpret_cast<const f16x8*>(wp);
        const f16x8 b1 = *reinterpret_cast<const f16x8*>(wp + 32);
        f32x4 c_ = {0.f, 0.f, 0.f, 0.f};
        c_ = __builtin_amdgcn_mfma_f32_16x16x32_f16(a0, b0, c_, 0, 0, 0);
        c_ = __builtin_amdgcn_mfma_f32_16x16x32_f16(a1, b1, c_, 0, 0, 0);
        acc[ob] = c_;
    }

    _Float16* ybase = yc + ((size_t)b * NN + n0 + wv * 16 + lg * 4) * 128 + lr;
#pragma unroll
    for (int ob = 0; ob < 8; ++ob)
#pragma unroll
        for (int r = 0; r < 4; ++r)
            ybase[(size_t)r * 128 + ob * 16] = (_Float16)acc[ob][r];
}

// ---------------------------------------------------------------------------
// Pass 2 (lane-per-n layout): lane = (nsub = lane>>4, q = lane&15); each lane
// owns one n and channel-quad q, iterates all 20 k. Packed fp16 max/min;
// f32x4 vector sum/ssq (compiler emits v_pk_add_f32 / v_pk_fma_f32).
// Cross-lane reduce once per wave. hmm fp16 row = [64 max][64 min].
// ---------------------------------------------------------------------------
__global__ __launch_bounds__(256, 4) void pass2_gather(const _Float16* __restrict__ yc,
                                                       const int* __restrict__ eidx,
                                                       __half* __restrict__ hmm,
                                                       float* __restrict__ psum,
                                                       float* __restrict__ pssq) {
    const int b  = blockIdx.x & 7;
    const int n0 = (blockIdx.x >> 3) * 32;
    const int w    = threadIdx.x >> 6;
    const int lane = threadIdx.x & 63;
    const int nsub = lane >> 4;
    const int q    = lane & 15;

    const int* e0 = eidx + (size_t)b * NN * KK;
    const int* e1 = e0 + (size_t)BB * NN * KK;
    const _Float16* yca = yc + (size_t)b * NN * 128 + 4 * q;   // wa cols
    const _Float16* ycb = yca + 64;                             // wb cols

    f32x4 sum4 = {0.f, 0.f, 0.f, 0.f};
    f32x4 ssq4 = {0.f, 0.f, 0.f, 0.f};

    for (int it = 0; it < 2; ++it) {
        const int n = n0 + w * 8 + it * 4 + nsub;
        const int4* p1 = reinterpret_cast<const int4*>(e1 + (size_t)n * KK);
        const int4* p0 = reinterpret_cast<const int4*>(e0 + (size_t)n * KK);
        int i1k[20], i0k[20];
#pragma unroll
        for (int c4 = 0; c4 < 5; ++c4) {
            int4 a = p1[c4];
            i1k[4 * c4 + 0] = a.x; i1k[4 * c4 + 1] = a.y;
            i1k[4 * c4 + 2] = a.z; i1k[4 * c4 + 3] = a.w;
            int4 c = p0[c4];
            i0k[4 * c4 + 0] = c.x; i0k[4 * c4 + 1] = c.y;
            i0k[4 * c4 + 2] = c.z; i0k[4 * c4 + 3] = c.w;
        }

        f16x4 hmx = {(_Float16)-65504.f, (_Float16)-65504.f,
                     (_Float16)-65504.f, (_Float16)-65504.f};
        f16x4 hmn = {(_Float16)65504.f, (_Float16)65504.f,
                     (_Float16)65504.f, (_Float16)65504.f};
#pragma unroll
        for (int k = 0; k < KK; ++k) {
            f16x4 v1 = *reinterpret_cast<const f16x4*>(yca + (size_t)i1k[k] * 128);
            f16x4 v0 = *reinterpret_cast<const f16x4*>(ycb + (size_t)i0k[k] * 128);
            f16x4 h = v1 + v0;                       // v_pk_add_f16
            hmx = __builtin_elementwise_max(hmx, h); // v_pk_max_f16
            hmn = __builtin_elementwise_min(hmn, h);
            f32x4 hf = {(float)h[0], (float)h[1], (float)h[2], (float)h[3]};
            sum4 += hf;                              // v_pk_add_f32
            ssq4 = __builtin_elementwise_fma(hf, hf, ssq4); // v_pk_fma_f32
        }
        union { f16x4 v; uint2 u; } px, pn;
        px.v = hmx; pn.v = hmn;
        __half* row = hmm + ((size_t)b * NN + n) * 128;
        *reinterpret_cast<uint2*>(row + 4 * q)      = px.u;
        *reinterpret_cast<uint2*>(row + 64 + 4 * q) = pn.u;
    }

    // cross-lane sum/ssq reduce over nsub (once per wave)
#pragma unroll
    for (int m = 16; m <= 32; m <<= 1) {
#pragma unroll
        for (int i = 0; i < 4; ++i) {
            sum4[i] += __shfl_xor(sum4[i], m);
            ssq4[i] += __shfl_xor(ssq4[i], m);
        }
    }
    __shared__ float rs[4][64], rq[4][64];
    if (nsub == 0) {
        *reinterpret_cast<f32x4*>(&rs[w][4 * q]) = sum4;
        *reinterpret_cast<f32x4*>(&rq[w][4 * q]) = ssq4;
    }
    __syncthreads();
    if (w == 0) {
        float s = rs[0][lane] + rs[1][lane] + rs[2][lane] + rs[3][lane];
        float qq = rq[0][lane] + rq[1][lane] + rq[2][lane] + rq[3][lane];
        psum[(size_t)blockIdx.x * 64 + lane] = s;
        pssq[(size_t)blockIdx.x * 64 + lane] = qq;
    }
}

// ---------------------------------------------------------------------------
// Pass 2b stage 1: 32 blocks reduce the 2048 partial rows.
// ---------------------------------------------------------------------------
__global__ __launch_bounds__(256) void pass2b_stage1(const float* __restrict__ psum,
                                                     const float* __restrict__ pssq,
                                                     double* __restrict__ p2sum,
                                                     double* __restrict__ p2ssq,
                                                     int nblocks) {
    const int t = threadIdx.x;
    const int c = t & 63, s = t >> 6;
    double sum = 0.0, ssq = 0.0;
    for (int i = blockIdx.x * 4 + s; i < nblocks; i += 32 * 4) {
        sum += (double)psum[(size_t)i * 64 + c];
        ssq += (double)pssq[(size_t)i * 64 + c];
    }
    __shared__ double ds_[4][64], dq_[4][64];
    ds_[s][c] = sum;
    dq_[s][c] = ssq;
    __syncthreads();
    if (s == 0) {
        p2sum[(size_t)blockIdx.x * 64 + c] = ds_[0][c] + ds_[1][c] + ds_[2][c] + ds_[3][c];
        p2ssq[(size_t)blockIdx.x * 64 + c] = dq_[0][c] + dq_[1][c] + dq_[2][c] + dq_[3][c];
    }
}

// ---------------------------------------------------------------------------
// Pass 2b stage 2: single block -> scale/shift.
// ---------------------------------------------------------------------------
__global__ __launch_bounds__(256) void pass2b_stage2(const double* __restrict__ p2sum,
                                                     const double* __restrict__ p2ssq,
                                                     const float* __restrict__ gamma,
                                                     const float* __restrict__ beta,
                                                     float* __restrict__ scsh) {
    const int t = threadIdx.x;
    const int c = t & 63, s = t >> 6;
    double sum = 0.0, ssq = 0.0;
    for (int i = s; i < 32; i += 4) {
        sum += p2sum[(size_t)i * 64 + c];
        ssq += p2ssq[(size_t)i * 64 + c];
    }
    __shared__ double ds_[4][64], dq_[4][64];
    ds_[s][c] = sum;
    dq_[s][c] = ssq;
    __syncthreads();
    if (s == 0) {
        double S = ds_[0][c] + ds_[1][c] + ds_[2][c] + ds_[3][c];
        double Q = dq_[0][c] + dq_[1][c] + dq_[2][c] + dq_[3][c];
        const double cnt = (double)BB * NN * KK;
        double mean = S / cnt;
        double var  = Q / cnt - mean * mean;
        float scale = (float)((double)gamma[c] / sqrt(var + BN_EPS));
        float shift = (float)((double)beta[c] - mean * (double)scale);
        scsh[c]      = scale;
        scsh[64 + c] = shift;
    }
}

// ---------------------------------------------------------------------------
// Pass 4: out[b][o][n] = relu(scale[o]*hsel + shift[o]); hmm rows are fp16.
// ---------------------------------------------------------------------------
__global__ __launch_bounds__(256) void pass4_out(const __half* __restrict__ hmm,
                                                 const float* __restrict__ scsh,
                                                 float* __restrict__ out) {
    const int b  = blockIdx.x & 7;
    const int n0 = (blockIdx.x >> 3) * 64;
    const int w    = threadIdx.x >> 6;
    const int lane = threadIdx.x & 63;

    __shared__ float ts[64][65];
    const float sc = scsh[lane];
    const float sh = scsh[64 + lane];

    for (int i = 0; i < 16; ++i) {
        const int j = w + 4 * i;
        const __half* row = hmm + ((size_t)b * NN + n0 + j) * 128;
        float hv = (sc >= 0.f) ? __half2float(row[lane])
                               : __half2float(row[64 + lane]);
        ts[j][lane] = fmaxf(0.f, fmaf(sc, hv, sh));
    }
    __syncthreads();
    for (int i = 0; i < 16; ++i) {
        const int o = w + 4 * i;
        out[((size_t)b * COUT + o) * NN + n0 + lane] = ts[lane][o];
    }
}

// ---------------------------------------------------------------------------
extern "C" void kernel_launch(void* const* d_in, const int* in_sizes, int n_in,
                              void* d_out, int out_size, void* d_ws, size_t ws_size,
                              hipStream_t stream) {
    const float* x     = (const float*)d_in[0]; // [B, C, N, 1]
    const float* wgt   = (const float*)d_in[1]; // [64, 128]
    const float* gamma = (const float*)d_in[2]; // [64]
    const float* beta  = (const float*)d_in[3]; // [64]
    const int*   eidx  = (const int*)d_in[4];   // [2, B, N, K]
    float* out = (float*)d_out;                 // [B, 64, N]

    // workspace layout
    _Float16* yc  = (_Float16*)d_ws;                      // B*N*128 fp16 (16 MB)
    __half*   hmm = (__half*)(yc + (size_t)BB * NN * 128);// B*N*128 fp16 (16 MB)
    float*  psum  = (float*)(hmm + (size_t)BB * NN * 128);// 2048*64 f32
    float*  pssq  = psum + (size_t)2048 * 64;
    double* p2sum = (double*)(pssq + (size_t)2048 * 64);  // 32*64 f64
    double* p2ssq = p2sum + 32 * 64;
    float*  scsh  = (float*)(p2ssq + 32 * 64);            // 128 f32
    _Float16* wtT = (_Float16*)(scsh + 128);              // 128*64 fp16 (16 KB)

    const int nblk2 = BB * (NN / 32); // 2048

    hipLaunchKernelGGL(pass0_wt, dim3(32), dim3(256), 0, stream, wgt, wtT);
    hipLaunchKernelGGL(pass1_mfma, dim3(BB * (NN / 64)), dim3(256), 0, stream,
                       x, wtT, yc);
    hipLaunchKernelGGL(pass2_gather, dim3(nblk2), dim3(256), 0, stream,
                       yc, eidx, hmm, psum, pssq);
    hipLaunchKernelGGL(pass2b_stage1, dim3(32), dim3(256), 0, stream,
                       psum, pssq, p2sum, p2ssq, nblk2);
    hipLaunchKernelGGL(pass2b_stage2, dim3(1), dim3(256), 0, stream,
                       p2sum, p2ssq, gamma, beta, scsh);
    hipLaunchKernelGGL(pass4_out, dim3(BB * (NN / 64)), dim3(256), 0, stream,
                       hmm, scsh, out);
}

// Round 13
// 64.089 us; speedup vs baseline: 1.9516x; 1.0712x over previous
//
#include <hip/hip_runtime.h>
#include <hip/hip_fp16.h>
#include <math.h>

#define BB 8
#define CC 64
#define NN 8192
#define KK 20
#define COUT 64
#define BN_EPS 1e-5

typedef _Float16 f16x8 __attribute__((ext_vector_type(8)));
typedef _Float16 f16x4 __attribute__((ext_vector_type(4)));
typedef float f32x4 __attribute__((ext_vector_type(4)));

// XCD swizzle: blockIdx round-robins over 8 XCDs -> (blockIdx.x & 7) == XCD.
// Batch b pinned to XCD b keeps b's yc slice resident in that XCD's L2.

// ---------------------------------------------------------------------------
// Pass 1 (fused weight-prep + transpose + MFMA):
//   yc[b][n][o2] fp16 = sum_c x[b][c][n] * wt[o2][c]
//   wt[o2][c] = (o2<64) ? w[o2][c]-w[o2][64+c] : w[o2-64][64+c]
// Weights staged in LDS W[128][72] (pad 72: frag-read bank = (4lr+4lg)%32 ->
// 2-way, free). x f32 tile in LDS T[64][65], converted to fp16 at read.
//   A lane l: row n = l&15, k(c) = (l>>4)*8 + j
//   B lane l: col o = l&15, k(c) = (l>>4)*8 + j
//   D lane l: col = l&15, row = (l>>4)*4 + r      [verified layout, m89]
// ---------------------------------------------------------------------------
__global__ __launch_bounds__(256) void pass1_mfma(const float* __restrict__ x,
                                                  const float* __restrict__ w,
                                                  _Float16* __restrict__ yc) {
    const int blk = blockIdx.x;            // 1024 blocks
    const int b   = blk & 7;
    const int ng  = blk >> 3;              // 0..127
    const int n0  = ng * 64;
    const int tid = threadIdx.x;
    const int wv  = __builtin_amdgcn_readfirstlane(tid >> 6);
    const int lane = tid & 63;

    __shared__ float T[64][65];                 // T[c][n]
    __shared__ alignas(16) _Float16 W[128][72]; // W[o2][c]

    // stage weights (coalesced: consecutive tid -> consecutive c)
#pragma unroll
    for (int i = 0; i < 32; ++i) {
        const int idx = i * 256 + tid;
        const int o2 = idx >> 6;
        const int c  = idx & 63;
        float v;
        if (o2 < 64) v = w[o2 * 128 + c] - w[o2 * 128 + 64 + c];
        else         v = w[(o2 - 64) * 128 + 64 + c];
        W[o2][c] = (_Float16)v;
    }
    // stage x tile
    for (int c = wv; c < 64; c += 4)
        T[c][lane] = x[((size_t)b * CC + c) * NN + n0 + lane];
    __syncthreads();

    const int lr = lane & 15;
    const int lg = lane >> 4;

    f16x8 a0, a1;
#pragma unroll
    for (int j = 0; j < 8; ++j) {
        a0[j] = (_Float16)T[lg * 8 + j][wv * 16 + lr];
        a1[j] = (_Float16)T[32 + lg * 8 + j][wv * 16 + lr];
    }

    f32x4 acc[8];
#pragma unroll
    for (int ob = 0; ob < 8; ++ob) {
        const f16x8 b0 = *reinterpret_cast<const f16x8*>(&W[ob * 16 + lr][lg * 8]);
        const f16x8 b1 = *reinterpret_cast<const f16x8*>(&W[ob * 16 + lr][32 + lg * 8]);
        f32x4 c_ = {0.f, 0.f, 0.f, 0.f};
        c_ = __builtin_amdgcn_mfma_f32_16x16x32_f16(a0, b0, c_, 0, 0, 0);
        c_ = __builtin_amdgcn_mfma_f32_16x16x32_f16(a1, b1, c_, 0, 0, 0);
        acc[ob] = c_;
    }

    _Float16* ybase = yc + ((size_t)b * NN + n0 + wv * 16 + lg * 4) * 128 + lr;
#pragma unroll
    for (int ob = 0; ob < 8; ++ob)
#pragma unroll
        for (int r = 0; r < 4; ++r)
            ybase[(size_t)r * 128 + ob * 16] = (_Float16)acc[ob][r];
}

// ---------------------------------------------------------------------------
// Pass 2 (lane-per-n layout): lane = (nsub = lane>>4, q = lane&15); each lane
// owns one n and channel-quad q, iterates all 20 k. Gathers use a wave-uniform
// SGPR base + 32-bit element offset ((idx<<7)+4q) -> single v_lshl_add_u32
// per gather instead of a 64-bit VGPR address chain. Packed fp16 max/min;
// f32x4 vector sum/ssq. Cross-lane reduce once per wave.
// hmm fp16 row = [64 max][64 min].
// ---------------------------------------------------------------------------
__global__ __launch_bounds__(256, 4) void pass2_gather(const _Float16* __restrict__ yc,
                                                       const int* __restrict__ eidx,
                                                       __half* __restrict__ hmm,
                                                       float* __restrict__ psum,
                                                       float* __restrict__ pssq) {
    const int b  = blockIdx.x & 7;
    const int n0 = (blockIdx.x >> 3) * 32;
    const int w    = threadIdx.x >> 6;
    const int lane = threadIdx.x & 63;
    const int nsub = lane >> 4;
    const int q    = lane & 15;

    const int* e0 = eidx + (size_t)b * NN * KK;
    const int* e1 = e0 + (size_t)BB * NN * KK;
    const _Float16* ycB = yc + (size_t)b * NN * 128;   // block-uniform -> SGPR
    const int qo1 = 4 * q;         // wa cols offset
    const int qo0 = 64 + 4 * q;    // wb cols offset

    f32x4 sum4 = {0.f, 0.f, 0.f, 0.f};
    f32x4 ssq4 = {0.f, 0.f, 0.f, 0.f};

    for (int it = 0; it < 2; ++it) {
        const int n = n0 + w * 8 + it * 4 + nsub;
        const int4* p1 = reinterpret_cast<const int4*>(e1 + (size_t)n * KK);
        const int4* p0 = reinterpret_cast<const int4*>(e0 + (size_t)n * KK);
        int i1k[20], i0k[20];
#pragma unroll
        for (int c4 = 0; c4 < 5; ++c4) {
            int4 a = p1[c4];
            i1k[4 * c4 + 0] = a.x; i1k[4 * c4 + 1] = a.y;
            i1k[4 * c4 + 2] = a.z; i1k[4 * c4 + 3] = a.w;
            int4 c = p0[c4];
            i0k[4 * c4 + 0] = c.x; i0k[4 * c4 + 1] = c.y;
            i0k[4 * c4 + 2] = c.z; i0k[4 * c4 + 3] = c.w;
        }

        f16x4 hmx = {(_Float16)-65504.f, (_Float16)-65504.f,
                     (_Float16)-65504.f, (_Float16)-65504.f};
        f16x4 hmn = {(_Float16)65504.f, (_Float16)65504.f,
                     (_Float16)65504.f, (_Float16)65504.f};
#pragma unroll
        for (int k = 0; k < KK; ++k) {
            f16x4 v1 = *reinterpret_cast<const f16x4*>(ycB + ((i1k[k] << 7) + qo1));
            f16x4 v0 = *reinterpret_cast<const f16x4*>(ycB + ((i0k[k] << 7) + qo0));
            f16x4 h = v1 + v0;                       // v_pk_add_f16
            hmx = __builtin_elementwise_max(hmx, h); // v_pk_max_f16
            hmn = __builtin_elementwise_min(hmn, h);
            f32x4 hf = {(float)h[0], (float)h[1], (float)h[2], (float)h[3]};
            sum4 += hf;
            ssq4 = __builtin_elementwise_fma(hf, hf, ssq4);
        }
        union { f16x4 v; uint2 u; } px, pn;
        px.v = hmx; pn.v = hmn;
        __half* row = hmm + ((size_t)b * NN + n) * 128;
        *reinterpret_cast<uint2*>(row + 4 * q)      = px.u;
        *reinterpret_cast<uint2*>(row + 64 + 4 * q) = pn.u;
    }

    // cross-lane sum/ssq reduce over nsub (once per wave)
#pragma unroll
    for (int m = 16; m <= 32; m <<= 1) {
#pragma unroll
        for (int i = 0; i < 4; ++i) {
            sum4[i] += __shfl_xor(sum4[i], m);
            ssq4[i] += __shfl_xor(ssq4[i], m);
        }
    }
    __shared__ float rs[4][64], rq[4][64];
    if (nsub == 0) {
        *reinterpret_cast<f32x4*>(&rs[w][4 * q]) = sum4;
        *reinterpret_cast<f32x4*>(&rq[w][4 * q]) = ssq4;
    }
    __syncthreads();
    if (w == 0) {
        float s = rs[0][lane] + rs[1][lane] + rs[2][lane] + rs[3][lane];
        float qq = rq[0][lane] + rq[1][lane] + rq[2][lane] + rq[3][lane];
        psum[(size_t)blockIdx.x * 64 + lane] = s;
        pssq[(size_t)blockIdx.x * 64 + lane] = qq;
    }
}

// ---------------------------------------------------------------------------
// Pass 2b stage 1: 32 blocks reduce the 2048 partial rows -> 32 rows (f64).
// ---------------------------------------------------------------------------
__global__ __launch_bounds__(256) void pass2b_stage1(const float* __restrict__ psum,
                                                     const float* __restrict__ pssq,
                                                     double* __restrict__ p2sum,
                                                     double* __restrict__ p2ssq,
                                                     int nblocks) {
    const int t = threadIdx.x;
    const int c = t & 63, s = t >> 6;
    double sum = 0.0, ssq = 0.0;
    for (int i = blockIdx.x * 4 + s; i < nblocks; i += 32 * 4) {
        sum += (double)psum[(size_t)i * 64 + c];
        ssq += (double)pssq[(size_t)i * 64 + c];
    }
    __shared__ double ds_[4][64], dq_[4][64];
    ds_[s][c] = sum;
    dq_[s][c] = ssq;
    __syncthreads();
    if (s == 0) {
        p2sum[(size_t)blockIdx.x * 64 + c] = ds_[0][c] + ds_[1][c] + ds_[2][c] + ds_[3][c];
        p2ssq[(size_t)blockIdx.x * 64 + c] = dq_[0][c] + dq_[1][c] + dq_[2][c] + dq_[3][c];
    }
}

// ---------------------------------------------------------------------------
// Pass 4 (fused stats finalize + output): wave 0 reduces the 32 partial rows
// (16 KB, L2-broadcast, deterministic serial order) -> scale/shift in LDS;
// then out[b][o][n] = relu(scale[o]*hsel + shift[o]), hsel = sc>=0 ? max:min.
// ---------------------------------------------------------------------------
__global__ __launch_bounds__(256) void pass4_out(const __half* __restrict__ hmm,
                                                 const double* __restrict__ p2sum,
                                                 const double* __restrict__ p2ssq,
                                                 const float* __restrict__ gamma,
                                                 const float* __restrict__ beta,
                                                 float* __restrict__ out) {
    const int b  = blockIdx.x & 7;
    const int n0 = (blockIdx.x >> 3) * 64;
    const int w    = threadIdx.x >> 6;
    const int lane = threadIdx.x & 63;

    __shared__ float ssc[64], ssh[64];
    __shared__ float ts[64][65];

    if (w == 0) {
        double S = 0.0, Q = 0.0;
        for (int i = 0; i < 32; ++i) {
            S += p2sum[i * 64 + lane];
            Q += p2ssq[i * 64 + lane];
        }
        const double cnt = (double)BB * NN * KK;
        double mean = S / cnt;
        double var  = Q / cnt - mean * mean;
        float scale = (float)((double)gamma[lane] / sqrt(var + BN_EPS));
        float shift = (float)((double)beta[lane] - mean * (double)scale);
        ssc[lane] = scale;
        ssh[lane] = shift;
    }
    __syncthreads();

    const float sc = ssc[lane];
    const float sh = ssh[lane];

    for (int i = 0; i < 16; ++i) {
        const int j = w + 4 * i;
        const __half* row = hmm + ((size_t)b * NN + n0 + j) * 128;
        float hv = (sc >= 0.f) ? __half2float(row[lane])
                               : __half2float(row[64 + lane]);
        ts[j][lane] = fmaxf(0.f, fmaf(sc, hv, sh));
    }
    __syncthreads();
    for (int i = 0; i < 16; ++i) {
        const int o = w + 4 * i;
        out[((size_t)b * COUT + o) * NN + n0 + lane] = ts[lane][o];
    }
}

// ---------------------------------------------------------------------------
extern "C" void kernel_launch(void* const* d_in, const int* in_sizes, int n_in,
                              void* d_out, int out_size, void* d_ws, size_t ws_size,
                              hipStream_t stream) {
    const float* x     = (const float*)d_in[0]; // [B, C, N, 1]
    const float* wgt   = (const float*)d_in[1]; // [64, 128]
    const float* gamma = (const float*)d_in[2]; // [64]
    const float* beta  = (const float*)d_in[3]; // [64]
    const int*   eidx  = (const int*)d_in[4];   // [2, B, N, K]
    float* out = (float*)d_out;                 // [B, 64, N]

    // workspace layout
    _Float16* yc  = (_Float16*)d_ws;                      // B*N*128 fp16 (16 MB)
    __half*   hmm = (__half*)(yc + (size_t)BB * NN * 128);// B*N*128 fp16 (16 MB)
    float*  psum  = (float*)(hmm + (size_t)BB * NN * 128);// 2048*64 f32
    float*  pssq  = psum + (size_t)2048 * 64;
    double* p2sum = (double*)(pssq + (size_t)2048 * 64);  // 32*64 f64
    double* p2ssq = p2sum + 32 * 64;

    const int nblk2 = BB * (NN / 32); // 2048

    hipLaunchKernelGGL(pass1_mfma, dim3(BB * (NN / 64)), dim3(256), 0, stream,
                       x, wgt, yc);
    hipLaunchKernelGGL(pass2_gather, dim3(nblk2), dim3(256), 0, stream,
                       yc, eidx, hmm, psum, pssq);
    hipLaunchKernelGGL(pass2b_stage1, dim3(32), dim3(256), 0, stream,
                       psum, pssq, p2sum, p2ssq, nblk2);
    hipLaunchKernelGGL(pass4_out, dim3(BB * (NN / 64)), dim3(256), 0, stream,
                       hmm, p2sum, p2ssq, gamma, beta, out);
}

// Round 14
// 48.433 us; speedup vs baseline: 2.5824x; 1.3232x over previous
//
#include <hip/hip_runtime.h>
#include <hip/hip_fp16.h>
#include <math.h>

#define BB 8
#define CC 64
#define NN 8192
#define KK 20
#define COUT 64
#define BN_EPS 1e-5

typedef _Float16 f16x8 __attribute__((ext_vector_type(8)));
typedef _Float16 f16x4 __attribute__((ext_vector_type(4)));
typedef float f32x4 __attribute__((ext_vector_type(4)));

// XCD swizzle: blockIdx round-robins over 8 XCDs -> (blockIdx.x & 7) == XCD.
// Batch b pinned to XCD b keeps b's yc slice resident in that XCD's L2.

// ---------------------------------------------------------------------------
// Pass 1 (fused weight-prep + transpose + MFMA):
//   yc[b][n][o2] fp16 = sum_c x[b][c][n] * wt[o2][c]
//   wt[o2][c] = (o2<64) ? w[o2][c]-w[o2][64+c] : w[o2-64][64+c]
// ---------------------------------------------------------------------------
__global__ __launch_bounds__(256) void pass1_mfma(const float* __restrict__ x,
                                                  const float* __restrict__ w,
                                                  _Float16* __restrict__ yc) {
    const int blk = blockIdx.x;            // 1024 blocks
    const int b   = blk & 7;
    const int ng  = blk >> 3;              // 0..127
    const int n0  = ng * 64;
    const int tid = threadIdx.x;
    const int wv  = __builtin_amdgcn_readfirstlane(tid >> 6);
    const int lane = tid & 63;

    __shared__ float T[64][65];                 // T[c][n]
    __shared__ alignas(16) _Float16 W[128][72]; // W[o2][c]

#pragma unroll
    for (int i = 0; i < 32; ++i) {
        const int idx = i * 256 + tid;
        const int o2 = idx >> 6;
        const int c  = idx & 63;
        float v;
        if (o2 < 64) v = w[o2 * 128 + c] - w[o2 * 128 + 64 + c];
        else         v = w[(o2 - 64) * 128 + 64 + c];
        W[o2][c] = (_Float16)v;
    }
    for (int c = wv; c < 64; c += 4)
        T[c][lane] = x[((size_t)b * CC + c) * NN + n0 + lane];
    __syncthreads();

    const int lr = lane & 15;
    const int lg = lane >> 4;

    f16x8 a0, a1;
#pragma unroll
    for (int j = 0; j < 8; ++j) {
        a0[j] = (_Float16)T[lg * 8 + j][wv * 16 + lr];
        a1[j] = (_Float16)T[32 + lg * 8 + j][wv * 16 + lr];
    }

    f32x4 acc[8];
#pragma unroll
    for (int ob = 0; ob < 8; ++ob) {
        const f16x8 b0 = *reinterpret_cast<const f16x8*>(&W[ob * 16 + lr][lg * 8]);
        const f16x8 b1 = *reinterpret_cast<const f16x8*>(&W[ob * 16 + lr][32 + lg * 8]);
        f32x4 c_ = {0.f, 0.f, 0.f, 0.f};
        c_ = __builtin_amdgcn_mfma_f32_16x16x32_f16(a0, b0, c_, 0, 0, 0);
        c_ = __builtin_amdgcn_mfma_f32_16x16x32_f16(a1, b1, c_, 0, 0, 0);
        acc[ob] = c_;
    }

    _Float16* ybase = yc + ((size_t)b * NN + n0 + wv * 16 + lg * 4) * 128 + lr;
#pragma unroll
    for (int ob = 0; ob < 8; ++ob)
#pragma unroll
        for (int r = 0; r < 4; ++r)
            ybase[(size_t)r * 128 + ob * 16] = (_Float16)acc[ob][r];
}

// ---------------------------------------------------------------------------
// Pass 2 (16B-per-lane gathers): lane = (nsub = lane>>3, q8 = lane&7).
// Each lane owns one n and channel octet q8 (8 ch = 16B), iterating all 20 k:
// 40 f16x8 gathers/lane, 1KB per wave instruction (vs 512B at 8B/lane) ->
// half the VMEM instructions / TA address work for the same bytes.
// Packed fp16 max/min; 2x f32x4 sum/ssq. Cross-lane reduce (strides 8/16/32)
// once per wave. hmm fp16 row = [64 max][64 min].
// ---------------------------------------------------------------------------
__global__ __launch_bounds__(256, 4) void pass2_gather(const _Float16* __restrict__ yc,
                                                       const int* __restrict__ eidx,
                                                       __half* __restrict__ hmm,
                                                       float* __restrict__ psum,
                                                       float* __restrict__ pssq) {
    const int b  = blockIdx.x & 7;
    const int n0 = (blockIdx.x >> 3) * 32;
    const int w    = threadIdx.x >> 6;
    const int lane = threadIdx.x & 63;
    const int nsub = lane >> 3;   // 0..7: which n this lane serves
    const int q8   = lane & 7;    // channel octet

    const int n = n0 + w * 8 + nsub;
    const int* e0 = eidx + (size_t)b * NN * KK;
    const int* e1 = e0 + (size_t)BB * NN * KK;
    const _Float16* ycB = yc + (size_t)b * NN * 128;   // block-uniform -> SGPR
    const int qo1 = 8 * q8;         // wa octet offset
    const int qo0 = 64 + 8 * q8;    // wb octet offset

    // preload this n's 40 indices (8 lanes/group load the same rows: L1 broadcast)
    const int4* p1 = reinterpret_cast<const int4*>(e1 + (size_t)n * KK);
    const int4* p0 = reinterpret_cast<const int4*>(e0 + (size_t)n * KK);
    int i1k[20], i0k[20];
#pragma unroll
    for (int c4 = 0; c4 < 5; ++c4) {
        int4 a = p1[c4];
        i1k[4 * c4 + 0] = a.x; i1k[4 * c4 + 1] = a.y;
        i1k[4 * c4 + 2] = a.z; i1k[4 * c4 + 3] = a.w;
        int4 c = p0[c4];
        i0k[4 * c4 + 0] = c.x; i0k[4 * c4 + 1] = c.y;
        i0k[4 * c4 + 2] = c.z; i0k[4 * c4 + 3] = c.w;
    }

    f16x8 hmx, hmn;
#pragma unroll
    for (int j = 0; j < 8; ++j) { hmx[j] = (_Float16)-65504.f; hmn[j] = (_Float16)65504.f; }
    f32x4 sumA = {0.f, 0.f, 0.f, 0.f}, sumB = {0.f, 0.f, 0.f, 0.f};
    f32x4 ssqA = {0.f, 0.f, 0.f, 0.f}, ssqB = {0.f, 0.f, 0.f, 0.f};

#pragma unroll
    for (int k = 0; k < KK; ++k) {
        f16x8 v1 = *reinterpret_cast<const f16x8*>(ycB + ((i1k[k] << 7) + qo1));
        f16x8 v0 = *reinterpret_cast<const f16x8*>(ycB + ((i0k[k] << 7) + qo0));
        f16x8 h = v1 + v0;                       // 4x v_pk_add_f16
        hmx = __builtin_elementwise_max(hmx, h); // 4x v_pk_max_f16
        hmn = __builtin_elementwise_min(hmn, h);
        f32x4 hA = {(float)h[0], (float)h[1], (float)h[2], (float)h[3]};
        f32x4 hB = {(float)h[4], (float)h[5], (float)h[6], (float)h[7]};
        sumA += hA; sumB += hB;
        ssqA = __builtin_elementwise_fma(hA, hA, ssqA);
        ssqB = __builtin_elementwise_fma(hB, hB, ssqB);
    }

    // store max/min octets (16B each)
    union { f16x8 v; uint4 u; } px, pn;
    px.v = hmx; pn.v = hmn;
    __half* row = hmm + ((size_t)b * NN + n) * 128;
    *reinterpret_cast<uint4*>(row + qo1)      = px.u;
    *reinterpret_cast<uint4*>(row + 64 + qo1) = pn.u;

    // cross-lane sum/ssq reduce over the 8 nsub groups (once per wave)
#pragma unroll
    for (int m = 8; m <= 32; m <<= 1) {
#pragma unroll
        for (int i = 0; i < 4; ++i) {
            sumA[i] += __shfl_xor(sumA[i], m);
            sumB[i] += __shfl_xor(sumB[i], m);
            ssqA[i] += __shfl_xor(ssqA[i], m);
            ssqB[i] += __shfl_xor(ssqB[i], m);
        }
    }
    __shared__ float rs[4][64], rq[4][64];
    if (nsub == 0) {   // lanes 0..7 hold channels 8*q8 .. 8*q8+7
        *reinterpret_cast<f32x4*>(&rs[w][8 * q8])     = sumA;
        *reinterpret_cast<f32x4*>(&rs[w][8 * q8 + 4]) = sumB;
        *reinterpret_cast<f32x4*>(&rq[w][8 * q8])     = ssqA;
        *reinterpret_cast<f32x4*>(&rq[w][8 * q8 + 4]) = ssqB;
    }
    __syncthreads();
    if (w == 0) {
        float s = rs[0][lane] + rs[1][lane] + rs[2][lane] + rs[3][lane];
        float qq = rq[0][lane] + rq[1][lane] + rq[2][lane] + rq[3][lane];
        psum[(size_t)blockIdx.x * 64 + lane] = s;
        pssq[(size_t)blockIdx.x * 64 + lane] = qq;
    }
}

// ---------------------------------------------------------------------------
// Pass 2b stage 1: 32 blocks reduce the 2048 partial rows -> 32 rows (f64).
// ---------------------------------------------------------------------------
__global__ __launch_bounds__(256) void pass2b_stage1(const float* __restrict__ psum,
                                                     const float* __restrict__ pssq,
                                                     double* __restrict__ p2sum,
                                                     double* __restrict__ p2ssq,
                                                     int nblocks) {
    const int t = threadIdx.x;
    const int c = t & 63, s = t >> 6;
    double sum = 0.0, ssq = 0.0;
    for (int i = blockIdx.x * 4 + s; i < nblocks; i += 32 * 4) {
        sum += (double)psum[(size_t)i * 64 + c];
        ssq += (double)pssq[(size_t)i * 64 + c];
    }
    __shared__ double ds_[4][64], dq_[4][64];
    ds_[s][c] = sum;
    dq_[s][c] = ssq;
    __syncthreads();
    if (s == 0) {
        p2sum[(size_t)blockIdx.x * 64 + c] = ds_[0][c] + ds_[1][c] + ds_[2][c] + ds_[3][c];
        p2ssq[(size_t)blockIdx.x * 64 + c] = dq_[0][c] + dq_[1][c] + dq_[2][c] + dq_[3][c];
    }
}

// ---------------------------------------------------------------------------
// Pass 4 (fused stats finalize + output): wave 0 reduces the 32 partial rows
// -> scale/shift in LDS; out[b][o][n] = relu(scale*hsel + shift).
// ---------------------------------------------------------------------------
__global__ __launch_bounds__(256) void pass4_out(const __half* __restrict__ hmm,
                                                 const double* __restrict__ p2sum,
                                                 const double* __restrict__ p2ssq,
                                                 const float* __restrict__ gamma,
                                                 const float* __restrict__ beta,
                                                 float* __restrict__ out) {
    const int b  = blockIdx.x & 7;
    const int n0 = (blockIdx.x >> 3) * 64;
    const int w    = threadIdx.x >> 6;
    const int lane = threadIdx.x & 63;

    __shared__ float ssc[64], ssh[64];
    __shared__ float ts[64][65];

    if (w == 0) {
        double S = 0.0, Q = 0.0;
        for (int i = 0; i < 32; ++i) {
            S += p2sum[i * 64 + lane];
            Q += p2ssq[i * 64 + lane];
        }
        const double cnt = (double)BB * NN * KK;
        double mean = S / cnt;
        double var  = Q / cnt - mean * mean;
        float scale = (float)((double)gamma[lane] / sqrt(var + BN_EPS));
        float shift = (float)((double)beta[lane] - mean * (double)scale);
        ssc[lane] = scale;
        ssh[lane] = shift;
    }
    __syncthreads();

    const float sc = ssc[lane];
    const float sh = ssh[lane];

    for (int i = 0; i < 16; ++i) {
        const int j = w + 4 * i;
        const __half* row = hmm + ((size_t)b * NN + n0 + j) * 128;
        float hv = (sc >= 0.f) ? __half2float(row[lane])
                               : __half2float(row[64 + lane]);
        ts[j][lane] = fmaxf(0.f, fmaf(sc, hv, sh));
    }
    __syncthreads();
    for (int i = 0; i < 16; ++i) {
        const int o = w + 4 * i;
        out[((size_t)b * COUT + o) * NN + n0 + lane] = ts[lane][o];
    }
}

// ---------------------------------------------------------------------------
extern "C" void kernel_launch(void* const* d_in, const int* in_sizes, int n_in,
                              void* d_out, int out_size, void* d_ws, size_t ws_size,
                              hipStream_t stream) {
    const float* x     = (const float*)d_in[0]; // [B, C, N, 1]
    const float* wgt   = (const float*)d_in[1]; // [64, 128]
    const float* gamma = (const float*)d_in[2]; // [64]
    const float* beta  = (const float*)d_in[3]; // [64]
    const int*   eidx  = (const int*)d_in[4];   // [2, B, N, K]
    float* out = (float*)d_out;                 // [B, 64, N]

    // workspace layout
    _Float16* yc  = (_Float16*)d_ws;                      // B*N*128 fp16 (16 MB)
    __half*   hmm = (__half*)(yc + (size_t)BB * NN * 128);// B*N*128 fp16 (16 MB)
    float*  psum  = (float*)(hmm + (size_t)BB * NN * 128);// 2048*64 f32
    float*  pssq  = psum + (size_t)2048 * 64;
    double* p2sum = (double*)(pssq + (size_t)2048 * 64);  // 32*64 f64
    double* p2ssq = p2sum + 32 * 64;

    const int nblk2 = BB * (NN / 32); // 2048

    hipLaunchKernelGGL(pass1_mfma, dim3(BB * (NN / 64)), dim3(256), 0, stream,
                       x, wgt, yc);
    hipLaunchKernelGGL(pass2_gather, dim3(nblk2), dim3(256), 0, stream,
                       yc, eidx, hmm, psum, pssq);
    hipLaunchKernelGGL(pass2b_stage1, dim3(32), dim3(256), 0, stream,
                       psum, pssq, p2sum, p2ssq, nblk2);
    hipLaunchKernelGGL(pass4_out, dim3(BB * (NN / 64)), dim3(256), 0, stream,
                       hmm, p2sum, p2ssq, gamma, beta, out);
}